// Round 6
// baseline (396.644 us; speedup 1.0000x reference)
//
#include <hip/hip_runtime.h>
#include <hip/hip_bf16.h>

#define D_HID 2048
#define F_EXP 1408
#define E_NUM 8
#define FS_SH 2816
#define T_TOK 2048

// bf16 element offsets inside the converted-weight block wb
#define O_WSG 0
#define O_WSU 5767168
#define O_WG  11534336
#define O_WU  34603008
#define O_WSD 57671680
#define O_WD  63438848
#define W_TOT 86507520

#define MAXT 24          // max routed 256-row tiles (sum ceil(cnt_e/256) <= 23)
#define GU_SH_BLK 176    // shared gateup: 22 ntiles * 8 mtiles
#define GU_GRID   440    // 176 + MAXT*11
#define DN_SH_BLK 128    // shared down:   16 ntiles * 8 mtiles

typedef __attribute__((ext_vector_type(8))) short bf16x8;
typedef __attribute__((ext_vector_type(4))) float f32x4;
typedef __attribute__((ext_vector_type(4))) unsigned short u16x4;

#define AS1 __attribute__((address_space(1)))
#define AS3 __attribute__((address_space(3)))

__device__ __forceinline__ unsigned short f2bf(float f){
  unsigned u = __float_as_uint(f);
  u += 0x7fffu + ((u >> 16) & 1u);          // RNE
  return (unsigned short)(u >> 16);
}

// ---------------- x fp32 -> bf16 ----------------
__global__ void convert_x_kernel(const float* __restrict__ x, unsigned short* __restrict__ xb){
  const int i = blockIdx.x * blockDim.x + threadIdx.x;
  float4 v = ((const float4*)x)[i];
  u16x4 h;
  h[0]=f2bf(v.x); h[1]=f2bf(v.y); h[2]=f2bf(v.z); h[3]=f2bf(v.w);
  ((u16x4*)xb)[i] = h;
}

// ---------------- gate/up weights fp32 -> bf16 (region [0, O_WSD)) ----------------
__global__ __launch_bounds__(256) void convert_w_kernel(
    const float* __restrict__ Wsg, const float* __restrict__ Wsu,
    const float* __restrict__ Wg,  const float* __restrict__ Wu,
    unsigned short* __restrict__ dst)
{
  const long e0 = ((long)blockIdx.x * 256 + threadIdx.x) * 8;
  const float* src; long lo;
  if      (e0 < (long)O_WSU){ src = Wsg; lo = e0 - O_WSG; }
  else if (e0 < (long)O_WG ){ src = Wsu; lo = e0 - O_WSU; }
  else if (e0 < (long)O_WU ){ src = Wg;  lo = e0 - O_WG;  }
  else                      { src = Wu;  lo = e0 - O_WU;  }
  const float4 a = ((const float4*)(src + lo))[0];
  const float4 b = ((const float4*)(src + lo))[1];
  u16x4 h0, h1;
  h0[0]=f2bf(a.x); h0[1]=f2bf(a.y); h0[2]=f2bf(a.z); h0[3]=f2bf(a.w);
  h1[0]=f2bf(b.x); h1[1]=f2bf(b.y); h1[2]=f2bf(b.z); h1[3]=f2bf(b.w);
  ((u16x4*)(dst + e0))[0] = h0;
  ((u16x4*)(dst + e0))[1] = h1;
}

// ---------------- router: logits, softmax, top-2 ----------------
__global__ __launch_bounds__(64) void router_kernel(const float* __restrict__ x,
                                                    const float* __restrict__ Wr,
                                                    int* __restrict__ topk_e,
                                                    float* __restrict__ topk_w){
  const int t = blockIdx.x;
  const int lane = threadIdx.x;
  const float* xt = x + (size_t)t * D_HID;
  float acc[E_NUM];
  #pragma unroll
  for (int e=0;e<E_NUM;e++) acc[e]=0.f;
  for (int d=lane; d<D_HID; d+=64){
    const float xv = xt[d];
    #pragma unroll
    for (int e=0;e<E_NUM;e++) acc[e] += xv * Wr[e*D_HID + d];
  }
  #pragma unroll
  for (int e=0;e<E_NUM;e++){
    #pragma unroll
    for (int off=32; off>0; off>>=1) acc[e] += __shfl_xor(acc[e], off);
  }
  if (lane==0){
    float m = acc[0];
    #pragma unroll
    for (int e=1;e<E_NUM;e++) m = fmaxf(m, acc[e]);
    float p[E_NUM]; float s = 0.f;
    #pragma unroll
    for (int e=0;e<E_NUM;e++){ p[e] = expf(acc[e]-m); s += p[e]; }
    const float inv = 1.f/s;
    int i0=0; float b0=p[0];
    #pragma unroll
    for (int e=1;e<E_NUM;e++) if (p[e] > b0){ b0=p[e]; i0=e; }
    int i1=-1; float b1=-1.f;
    #pragma unroll
    for (int e=0;e<E_NUM;e++) if (e!=i0 && p[e] > b1){ b1=p[e]; i1=e; }
    topk_e[t*2+0]=i0; topk_e[t*2+1]=i1;
    topk_w[t*2+0]=b0*inv; topk_w[t*2+1]=b1*inv;
  }
}

// ---------------- deterministic expert-grouped list build + tile records ----------------
__global__ __launch_bounds__(1024) void build_lists_kernel(
    const int* __restrict__ topk_e, const float* __restrict__ topk_w,
    int* __restrict__ cnt, int* __restrict__ offs,
    int* __restrict__ assign_token, float* __restrict__ assign_w,
    int* __restrict__ token_slot,
    int* __restrict__ tile_rowbase, int* __restrict__ tile_e,
    int* __restrict__ tile_valid, int* __restrict__ n_rt)
{
  const int tid  = threadIdx.x;
  const int lane = tid & 63;
  const int wv   = tid >> 6;                 // 16 waves
  __shared__ int wsum[E_NUM][16];
  __shared__ int tot_s[E_NUM];
  __shared__ int offs_s[E_NUM];

  int   e_loc[4];
  float w_loc[4];
  #pragma unroll
  for (int j=0;j<4;j++){ e_loc[j]=topk_e[tid*4+j]; w_loc[j]=topk_w[tid*4+j]; }

  int c[E_NUM];
  #pragma unroll
  for (int e=0;e<E_NUM;e++){
    int s = 0;
    #pragma unroll
    for (int j=0;j<4;j++) s += (e_loc[j]==e) ? 1 : 0;
    c[e] = s;
  }
  int pre[E_NUM];
  #pragma unroll
  for (int e=0;e<E_NUM;e++){
    int v = c[e];
    #pragma unroll
    for (int off=1; off<64; off<<=1){
      int t = __shfl_up(v, off);
      if (lane >= off) v += t;
    }
    if (lane==63) wsum[e][wv] = v;
    pre[e] = v - c[e];
  }
  __syncthreads();
  if (tid < E_NUM){
    int s = 0;
    #pragma unroll
    for (int w=0; w<16; w++){ int t = wsum[tid][w]; wsum[tid][w] = s; s += t; }
    tot_s[tid] = s;
    cnt[tid]   = s;
  }
  __syncthreads();
  if (tid == 0){
    int s = 0;
    #pragma unroll
    for (int e=0;e<E_NUM;e++){ offs_s[e] = s; offs[e] = s; s += tot_s[e]; }
    int ntl = 0;
    for (int e=0;e<E_NUM;e++){
      for (int r=0; r<tot_s[e]; r+=256){
        tile_rowbase[ntl] = offs_s[e] + r;
        tile_e[ntl]       = e;
        int v = tot_s[e] - r; if (v > 256) v = 256;
        tile_valid[ntl]   = v;
        ntl++;
      }
    }
    n_rt[0] = ntl;
    for (int i=ntl;i<MAXT;i++){ tile_rowbase[i]=0; tile_e[i]=0; tile_valid[i]=0; }
  }
  __syncthreads();
  int local[E_NUM];
  #pragma unroll
  for (int e=0;e<E_NUM;e++) local[e]=0;
  #pragma unroll
  for (int j=0;j<4;j++){
    const int e = e_loc[j];
    int pos = 0;
    #pragma unroll
    for (int ee=0; ee<E_NUM; ee++)
      if (e == ee) pos = offs_s[ee] + wsum[ee][wv] + pre[ee] + local[ee];
    #pragma unroll
    for (int ee=0; ee<E_NUM; ee++) local[ee] += (e == ee) ? 1 : 0;
    const int entry = tid*4 + j;
    assign_token[pos] = entry >> 1;
    assign_w[pos]     = w_loc[j];
    token_slot[entry] = pos;
  }
}

// ================= fused gate+up GEMM, phase-interleaved (T3+T4+T5) =================
// 512 thr / 8 waves (4M x 2N), BM=256, BN=128, BK=64. LDS = 128 KB. 2-buf, 1-ahead.
// All blocks also convert the down-weight region (Wsd,Wd) fp32->bf16 as a preamble.
__global__ __launch_bounds__(512,1) void gateup_fused(
    const unsigned short* __restrict__ xb,
    unsigned short* __restrict__ wb,
    const float* __restrict__ Wsd_f, const float* __restrict__ Wd_f,
    unsigned short* __restrict__ h_shared,
    unsigned short* __restrict__ h_routed,
    const int* __restrict__ tile_rowbase, const int* __restrict__ tile_e,
    const int* __restrict__ tile_valid, const int* __restrict__ n_rt,
    const int* __restrict__ assign_token)
{
  __shared__ __align__(16) char As[2][256*128];   // 64 KB
  __shared__ __align__(16) char Bg[2][128*128];   // 32 KB
  __shared__ __align__(16) char Bu[2][128*128];   // 32 KB

  const int tid  = threadIdx.x;
  const int lane = tid & 63;
  const int wave = tid >> 6;       // 0..7
  const int wr = wave >> 1;        // 0..3
  const int wc = wave & 1;         // 0..1
  const int b = blockIdx.x;

  // ---- preamble: convert Wsd/Wd slice (exactly 16 iters: 440*512*16*8 = 28,835,840 elems)
  {
    const int nchunk = (W_TOT - O_WSD) / 8;       // 3,604,480
    for (int i = b*512 + tid; i < nchunk; i += GU_GRID*512){
      const long e0 = (long)O_WSD + (long)i * 8;
      const float* src; long lo;
      if (e0 < (long)O_WD){ src = Wsd_f; lo = e0 - O_WSD; } else { src = Wd_f; lo = e0 - O_WD; }
      const float4 va = ((const float4*)(src + lo))[0];
      const float4 vb = ((const float4*)(src + lo))[1];
      u16x4 h0, h1;
      h0[0]=f2bf(va.x); h0[1]=f2bf(va.y); h0[2]=f2bf(va.z); h0[3]=f2bf(va.w);
      h1[0]=f2bf(vb.x); h1[1]=f2bf(vb.y); h1[2]=f2bf(vb.z); h1[3]=f2bf(vb.w);
      ((u16x4*)(wb + e0))[0] = h0;
      ((u16x4*)(wb + e0))[1] = h1;
    }
  }

  int nt, rowbase, valid, gather;
  const unsigned short *wg_base, *wu_base;
  unsigned short* H; int N;
  if (b < GU_SH_BLK){
    nt = b >> 3; const int mtile = b & 7;       // 8 consecutive blocks share a weight panel
    rowbase = mtile*256; valid = 256; gather = 0;
    wg_base = wb + O_WSG + (size_t)(nt*128) * D_HID;
    wu_base = wb + O_WSU + (size_t)(nt*128) * D_HID;
    H = h_shared; N = FS_SH;
  } else {
    const int rb = b - GU_SH_BLK;
    const int tile = rb % MAXT;
    nt = rb / MAXT;                              // 0..10
    if (tile >= n_rt[0]) return;
    rowbase = tile_rowbase[tile];
    valid   = tile_valid[tile];
    const int e = tile_e[tile];
    gather = 1;
    wg_base = wb + O_WG + ((size_t)e*F_EXP + nt*128) * D_HID;
    wu_base = wb + O_WU + ((size_t)e*F_EXP + nt*128) * D_HID;
    H = h_routed; N = F_EXP;
  }

  f32x4 accg[4][4], accu[4][4];
  const f32x4 z = {0.f,0.f,0.f,0.f};
  #pragma unroll
  for (int m=0;m<4;m++)
    #pragma unroll
    for (int n=0;n<4;n++){ accg[m][n]=z; accu[m][n]=z; }

  const char* asrc[4];
  const int rowmax = rowbase + valid - 1;
  const int srccol = ((lane&7)<<4) ^ ((lane>>3)<<4);
  #pragma unroll
  for (int p=0;p<4;p++){
    const int row = wave*32 + p*8 + (lane>>3);
    int idx = rowbase + row;
    if (idx > rowmax) idx = rowmax;
    const size_t grow = gather ? (size_t)assign_token[idx] : (size_t)idx;
    asrc[p] = (const char*)(xb + grow * (size_t)D_HID) + srccol;
  }
  const int brow0 = wave*16 + (lane>>3);
  const char* gsrc = (const char*)(wg_base + (size_t)brow0 * D_HID) + srccol;
  const char* usrc = (const char*)(wu_base + (size_t)brow0 * D_HID) + srccol;
  const int pstrB = 8 * D_HID * 2;

  auto stage = [&](int bi, int kt){     // 8 loads per wave
    #pragma unroll
    for (int p=0;p<4;p++){
      __builtin_amdgcn_global_load_lds(
        (const AS1 void*)(asrc[p] + kt*128),
        (AS3 void*)(&As[bi][(wave*4 + p)*1024]), 16, 0, 0);
    }
    #pragma unroll
    for (int p=0;p<2;p++){
      __builtin_amdgcn_global_load_lds(
        (const AS1 void*)(gsrc + p*pstrB + kt*128),
        (AS3 void*)(&Bg[bi][(wave*2 + p)*1024]), 16, 0, 0);
      __builtin_amdgcn_global_load_lds(
        (const AS1 void*)(usrc + p*pstrB + kt*128),
        (AS3 void*)(&Bu[bi][(wave*2 + p)*1024]), 16, 0, 0);
    }
  };

  const int arow = wr*64 + (lane & 15);        // +m*16
  const int brow = wc*64 + (lane & 15);        // +n*16
  const int kq   = (lane >> 4) << 4;           // 16B quad offset within 64B half

  const int nK = D_HID / 64;   // 32
  stage(0, 0);
  asm volatile("s_waitcnt vmcnt(0)\n\ts_barrier" ::: "memory");
  int cur = 0;
  #pragma unroll 1
  for (int kt = 0; kt < nK; ++kt){
    // ---------- phase 0: gate, kk0 (reads a_kk0; stages ALL next-tile loads) ----------
    bf16x8 a0[4], bx[4];
    {
      const int kb = 0*64 + kq;
      #pragma unroll
      for (int m=0;m<4;m++){
        const int r = arow + m*16;
        a0[m] = *(const bf16x8*)(&As[cur][r*128 + (kb ^ ((r & 7) << 4))]);
      }
      #pragma unroll
      for (int n=0;n<4;n++){
        const int r = brow + n*16;
        bx[n] = *(const bf16x8*)(&Bg[cur][r*128 + (kb ^ ((r & 7) << 4))]);
      }
    }
    if (kt + 1 < nK) stage(cur^1, kt+1);
    asm volatile("s_barrier" ::: "memory");
    __builtin_amdgcn_sched_barrier(0);
    __builtin_amdgcn_s_setprio(1);
    #pragma unroll
    for (int m=0;m<4;m++)
      #pragma unroll
      for (int n=0;n<4;n++)
        accg[m][n] = __builtin_amdgcn_mfma_f32_16x16x32_bf16(a0[m], bx[n], accg[m][n], 0,0,0);
    __builtin_amdgcn_s_setprio(0);
    __builtin_amdgcn_sched_barrier(0);
    asm volatile("s_barrier" ::: "memory");
    // ---------- phase 1: up, kk0 (a0 reused) ----------
    {
      const int kb = 0*64 + kq;
      #pragma unroll
      for (int n=0;n<4;n++){
        const int r = brow + n*16;
        bx[n] = *(const bf16x8*)(&Bu[cur][r*128 + (kb ^ ((r & 7) << 4))]);
      }
    }
    asm volatile("s_barrier" ::: "memory");
    __builtin_amdgcn_sched_barrier(0);
    __builtin_amdgcn_s_setprio(1);
    #pragma unroll
    for (int m=0;m<4;m++)
      #pragma unroll
      for (int n=0;n<4;n++)
        accu[m][n] = __builtin_amdgcn_mfma_f32_16x16x32_bf16(a0[m], bx[n], accu[m][n], 0,0,0);
    __builtin_amdgcn_s_setprio(0);
    __builtin_amdgcn_sched_barrier(0);
    asm volatile("s_barrier" ::: "memory");
    // ---------- phase 2: gate, kk1 ----------
    bf16x8 a1[4];
    {
      const int kb = 1*64 + kq;
      #pragma unroll
      for (int m=0;m<4;m++){
        const int r = arow + m*16;
        a1[m] = *(const bf16x8*)(&As[cur][r*128 + (kb ^ ((r & 7) << 4))]);
      }
      #pragma unroll
      for (int n=0;n<4;n++){
        const int r = brow + n*16;
        bx[n] = *(const bf16x8*)(&Bg[cur][r*128 + (kb ^ ((r & 7) << 4))]);
      }
    }
    asm volatile("s_barrier" ::: "memory");
    __builtin_amdgcn_sched_barrier(0);
    __builtin_amdgcn_s_setprio(1);
    #pragma unroll
    for (int m=0;m<4;m++)
      #pragma unroll
      for (int n=0;n<4;n++)
        accg[m][n] = __builtin_amdgcn_mfma_f32_16x16x32_bf16(a1[m], bx[n], accg[m][n], 0,0,0);
    __builtin_amdgcn_s_setprio(0);
    __builtin_amdgcn_sched_barrier(0);
    asm volatile("s_barrier" ::: "memory");
    // ---------- phase 3: up, kk1 ----------
    {
      const int kb = 1*64 + kq;
      #pragma unroll
      for (int n=0;n<4;n++){
        const int r = brow + n*16;
        bx[n] = *(const bf16x8*)(&Bu[cur][r*128 + (kb ^ ((r & 7) << 4))]);
      }
    }
    asm volatile("s_barrier" ::: "memory");
    __builtin_amdgcn_sched_barrier(0);
    __builtin_amdgcn_s_setprio(1);
    #pragma unroll
    for (int m=0;m<4;m++)
      #pragma unroll
      for (int n=0;n<4;n++)
        accu[m][n] = __builtin_amdgcn_mfma_f32_16x16x32_bf16(a1[m], bx[n], accu[m][n], 0,0,0);
    __builtin_amdgcn_s_setprio(0);
    __builtin_amdgcn_sched_barrier(0);
    // end of K-step: next buffer landed (vmcnt) + all reads of cur done (barrier)
    asm volatile("s_waitcnt vmcnt(0)\n\ts_barrier" ::: "memory");
    cur ^= 1;
  }

  const int colbase = nt*128 + wc*64;
  #pragma unroll
  for (int m=0;m<4;m++){
    #pragma unroll
    for (int r=0;r<4;r++){
      const int rr = wr*64 + m*16 + ((lane >> 4) << 2) + r;
      if (rr < valid){
        unsigned short* orow = H + (size_t)(rowbase + rr) * N;
        #pragma unroll
        for (int n=0;n<4;n++){
          const int col = colbase + n*16 + (lane & 15);
          const float g = accg[m][n][r];
          const float u = accu[m][n][r];
          const float h = (g / (1.f + __expf(-g))) * u;
          orow[col] = f2bf(h);
        }
      }
    }
  }
}

// ================= fused down GEMM, phase-interleaved =================
__global__ __launch_bounds__(512,1) void down_fused(
    const unsigned short* __restrict__ h_shared,
    const unsigned short* __restrict__ h_routed,
    const unsigned short* __restrict__ wb,
    float* __restrict__ out, float* __restrict__ y_routed,
    const int* __restrict__ tile_rowbase, const int* __restrict__ tile_e,
    const int* __restrict__ tile_valid, const int* __restrict__ n_rt,
    const float* __restrict__ assign_w)
{
  __shared__ __align__(16) char As[2][256*128];   // 64 KB
  __shared__ __align__(16) char Bs[2][128*128];   // 32 KB

  const int tid  = threadIdx.x;
  const int lane = tid & 63;
  const int wave = tid >> 6;
  const int wr = wave >> 1, wc = wave & 1;
  const int b = blockIdx.x;

  int nt, rowbase, valid, weighted, K;
  const unsigned short *A, *w_base;
  float* Out;
  if (b < DN_SH_BLK){
    nt = b >> 3; const int mtile = b & 7;
    rowbase = mtile*256; valid = 256; weighted = 0;
    A = h_shared; K = FS_SH;
    w_base = wb + O_WSD + (size_t)(nt*128) * FS_SH;
    Out = out;
  } else {
    const int rb = b - DN_SH_BLK;
    const int tile = rb % MAXT;
    nt = rb / MAXT;                              // 0..15
    if (tile >= n_rt[0]) return;
    rowbase = tile_rowbase[tile];
    valid   = tile_valid[tile];
    const int e = tile_e[tile];
    weighted = 1;
    A = h_routed; K = F_EXP;
    w_base = wb + O_WD + ((size_t)e*D_HID + nt*128) * F_EXP;
    Out = y_routed;
  }
  const size_t K2 = (size_t)K * 2;

  f32x4 acc[4][4];
  const f32x4 z = {0.f,0.f,0.f,0.f};
  #pragma unroll
  for (int m=0;m<4;m++)
    #pragma unroll
    for (int n=0;n<4;n++) acc[m][n]=z;

  const char* asrc[4];
  const int rowmax = rowbase + valid - 1;
  const int srccol = ((lane&7)<<4) ^ ((lane>>3)<<4);
  #pragma unroll
  for (int p=0;p<4;p++){
    const int row = wave*32 + p*8 + (lane>>3);
    int idx = rowbase + row;
    if (idx > rowmax) idx = rowmax;
    asrc[p] = (const char*)A + (size_t)idx * K2 + srccol;
  }
  const int brow0 = wave*16 + (lane>>3);
  const char* bsrc = (const char*)w_base + (size_t)brow0 * K2 + srccol;
  const size_t pstrB = 8 * K2;

  auto stage = [&](int bi, int kt){      // 6 loads per wave
    #pragma unroll
    for (int p=0;p<4;p++){
      __builtin_amdgcn_global_load_lds(
        (const AS1 void*)(asrc[p] + kt*128),
        (AS3 void*)(&As[bi][(wave*4 + p)*1024]), 16, 0, 0);
    }
    #pragma unroll
    for (int p=0;p<2;p++){
      __builtin_amdgcn_global_load_lds(
        (const AS1 void*)(bsrc + p*pstrB + kt*128),
        (AS3 void*)(&Bs[bi][(wave*2 + p)*1024]), 16, 0, 0);
    }
  };

  const int arow = wr*64 + (lane & 15);
  const int brow = wc*64 + (lane & 15);
  const int kq   = (lane >> 4) << 4;

  const int nK = K / 64;       // 44 or 22
  stage(0, 0);
  asm volatile("s_waitcnt vmcnt(0)\n\ts_barrier" ::: "memory");
  int cur = 0;
  #pragma unroll 1
  for (int kt = 0; kt < nK; ++kt){
    // ---------- phase 0: kk0 (stages all next-tile loads) ----------
    bf16x8 a[4], bb[4];
    {
      const int kb = 0*64 + kq;
      #pragma unroll
      for (int m=0;m<4;m++){
        const int r = arow + m*16;
        a[m] = *(const bf16x8*)(&As[cur][r*128 + (kb ^ ((r & 7) << 4))]);
      }
      #pragma unroll
      for (int n=0;n<4;n++){
        const int r = brow + n*16;
        bb[n] = *(const bf16x8*)(&Bs[cur][r*128 + (kb ^ ((r & 7) << 4))]);
      }
    }
    if (kt + 1 < nK) stage(cur^1, kt+1);
    asm volatile("s_barrier" ::: "memory");
    __builtin_amdgcn_sched_barrier(0);
    __builtin_amdgcn_s_setprio(1);
    #pragma unroll
    for (int m=0;m<4;m++)
      #pragma unroll
      for (int n=0;n<4;n++)
        acc[m][n] = __builtin_amdgcn_mfma_f32_16x16x32_bf16(a[m], bb[n], acc[m][n], 0,0,0);
    __builtin_amdgcn_s_setprio(0);
    __builtin_amdgcn_sched_barrier(0);
    asm volatile("s_barrier" ::: "memory");
    // ---------- phase 1: kk1 ----------
    {
      const int kb = 1*64 + kq;
      #pragma unroll
      for (int m=0;m<4;m++){
        const int r = arow + m*16;
        a[m] = *(const bf16x8*)(&As[cur][r*128 + (kb ^ ((r & 7) << 4))]);
      }
      #pragma unroll
      for (int n=0;n<4;n++){
        const int r = brow + n*16;
        bb[n] = *(const bf16x8*)(&Bs[cur][r*128 + (kb ^ ((r & 7) << 4))]);
      }
    }
    asm volatile("s_barrier" ::: "memory");
    __builtin_amdgcn_sched_barrier(0);
    __builtin_amdgcn_s_setprio(1);
    #pragma unroll
    for (int m=0;m<4;m++)
      #pragma unroll
      for (int n=0;n<4;n++)
        acc[m][n] = __builtin_amdgcn_mfma_f32_16x16x32_bf16(a[m], bb[n], acc[m][n], 0,0,0);
    __builtin_amdgcn_s_setprio(0);
    __builtin_amdgcn_sched_barrier(0);
    asm volatile("s_waitcnt vmcnt(0)\n\ts_barrier" ::: "memory");
    cur ^= 1;
  }

  const int colbase = nt*128 + wc*64;
  #pragma unroll
  for (int m=0;m<4;m++){
    #pragma unroll
    for (int r=0;r<4;r++){
      const int rr = wr*64 + m*16 + ((lane >> 4) << 2) + r;
      if (rr < valid){
        float w = 1.f;
        if (weighted) w = assign_w[rowbase + rr];
        float* orow = Out + (size_t)(rowbase + rr) * D_HID;
        #pragma unroll
        for (int n=0;n<4;n++){
          const int col = colbase + n*16 + (lane & 15);
          orow[col] = acc[m][n][r] * w;
        }
      }
    }
  }
}

// ---------------- combine: out += y[slot0] + y[slot1] ----------------
__global__ void combine_kernel(float* __restrict__ out, const float* __restrict__ y,
                               const int* __restrict__ token_slot){
  const int i  = blockIdx.x * blockDim.x + threadIdx.x;
  const int t  = i >> 9;
  const int r4 = i & 511;
  const int s0 = token_slot[t*2+0];
  const int s1 = token_slot[t*2+1];
  const float4 a = ((const float4*)(y + (size_t)s0 * D_HID))[r4];
  const float4 b = ((const float4*)(y + (size_t)s1 * D_HID))[r4];
  float4 o = ((float4*)out)[i];
  o.x += a.x + b.x; o.y += a.y + b.y; o.z += a.z + b.z; o.w += a.w + b.w;
  ((float4*)out)[i] = o;
}

extern "C" void kernel_launch(void* const* d_in, const int* in_sizes, int n_in,
                              void* d_out, int out_size, void* d_ws, size_t ws_size,
                              hipStream_t stream){
  const float* x   = (const float*)d_in[0];
  const float* Wr  = (const float*)d_in[1];
  const float* Wg  = (const float*)d_in[2];
  const float* Wu  = (const float*)d_in[3];
  const float* Wd  = (const float*)d_in[4];
  const float* Wsg = (const float*)d_in[5];
  const float* Wsu = (const float*)d_in[6];
  const float* Wsd = (const float*)d_in[7];
  float* out = (float*)d_out;
  (void)in_sizes; (void)n_in; (void)out_size; (void)ws_size;

  char* ws = (char*)d_ws;
  size_t off = 0;
  auto alloc = [&](size_t bytes)->char*{
    char* p = ws + off; off += (bytes + 255) & ~(size_t)255; return p;
  };

  unsigned short* wb       = (unsigned short*)alloc((size_t)W_TOT * 2);
  unsigned short* xb       = (unsigned short*)alloc((size_t)T_TOK * D_HID * 2);
  unsigned short* h_shared = (unsigned short*)alloc((size_t)T_TOK * FS_SH * 2);
  unsigned short* h_routed = (unsigned short*)alloc((size_t)T_TOK * 2 * F_EXP * 2);
  float*          y_routed = (float*)alloc((size_t)T_TOK * 2 * D_HID * 4);
  int*   topk_e       = (int*)alloc(T_TOK*2*sizeof(int));
  float* topk_w       = (float*)alloc(T_TOK*2*sizeof(float));
  int*   cnt          = (int*)alloc(E_NUM*sizeof(int));
  int*   offs         = (int*)alloc(E_NUM*sizeof(int));
  int*   assign_token = (int*)alloc(T_TOK*2*sizeof(int));
  float* assign_w     = (float*)alloc(T_TOK*2*sizeof(float));
  int*   token_slot   = (int*)alloc(T_TOK*2*sizeof(int));
  int*   tile_rowbase = (int*)alloc(MAXT*sizeof(int));
  int*   tile_e       = (int*)alloc(MAXT*sizeof(int));
  int*   tile_valid   = (int*)alloc(MAXT*sizeof(int));
  int*   n_rt         = (int*)alloc(sizeof(int));

  convert_x_kernel<<<(T_TOK*D_HID/4)/256, 256, 0, stream>>>(x, xb);
  router_kernel<<<T_TOK, 64, 0, stream>>>(x, Wr, topk_e, topk_w);
  build_lists_kernel<<<1, 1024, 0, stream>>>(topk_e, topk_w, cnt, offs,
      assign_token, assign_w, token_slot, tile_rowbase, tile_e, tile_valid, n_rt);
  // convert only gate/up region; gateup_fused converts the down region itself
  convert_w_kernel<<<O_WSD/8/256, 256, 0, stream>>>(Wsg, Wsu, Wg, Wu, wb);

  gateup_fused<<<GU_GRID, 512, 0, stream>>>(
      xb, wb, Wsd, Wd, h_shared, h_routed, tile_rowbase, tile_e, tile_valid, n_rt, assign_token);
  down_fused<<<DN_SH_BLK + MAXT*(D_HID/128), 512, 0, stream>>>(
      h_shared, h_routed, wb, out, y_routed, tile_rowbase, tile_e, tile_valid, n_rt, assign_w);

  combine_kernel<<<(T_TOK*D_HID/4)/256, 256, 0, stream>>>(out, y_routed, token_slot);
}

// Round 7
// 388.076 us; speedup vs baseline: 1.0221x; 1.0221x over previous
//
#include <hip/hip_runtime.h>
#include <hip/hip_bf16.h>

#define D_HID 2048
#define F_EXP 1408
#define E_NUM 8
#define FS_SH 2816
#define T_TOK 2048

// bf16 element offsets inside the converted-weight block wb
#define O_WSG 0
#define O_WSU 5767168
#define O_WG  11534336
#define O_WU  34603008
#define O_WSD 57671680
#define O_WD  63438848
#define W_TOT 86507520

#define MAXT 24          // max routed 256-row tiles (sum ceil(cnt_e/256) <= 24)
#define GU_SH_BLK 176    // shared gateup: 22 ntiles * 8 mtiles
#define GU_GEMM   440    // 176 + MAXT*11   (= 8*55, XCD-divisible)
#define GU_CONV   64     // converter blocks appended to gateup grid
#define DN_GRID   512    // 128 + MAXT*16   (= 8*64)
#define DN_SH_BLK 128    // shared down:   16 ntiles * 8 mtiles

typedef __attribute__((ext_vector_type(8))) short bf16x8;
typedef __attribute__((ext_vector_type(4))) float f32x4;
typedef __attribute__((ext_vector_type(4))) unsigned short u16x4;

#define AS1 __attribute__((address_space(1)))
#define AS3 __attribute__((address_space(3)))

__device__ __forceinline__ unsigned short f2bf(float f){
  unsigned u = __float_as_uint(f);
  u += 0x7fffu + ((u >> 16) & 1u);          // RNE
  return (unsigned short)(u >> 16);
}

// ---------------- gate/up weights fp32 -> bf16 (region [0, O_WSD)) ----------------
__global__ __launch_bounds__(256) void convert_w_kernel(
    const float* __restrict__ Wsg, const float* __restrict__ Wsu,
    const float* __restrict__ Wg,  const float* __restrict__ Wu,
    unsigned short* __restrict__ dst)
{
  const long e0 = ((long)blockIdx.x * 256 + threadIdx.x) * 8;
  const float* src; long lo;
  if      (e0 < (long)O_WSU){ src = Wsg; lo = e0 - O_WSG; }
  else if (e0 < (long)O_WG ){ src = Wsu; lo = e0 - O_WSU; }
  else if (e0 < (long)O_WU ){ src = Wg;  lo = e0 - O_WG;  }
  else                      { src = Wu;  lo = e0 - O_WU;  }
  const float4 a = ((const float4*)(src + lo))[0];
  const float4 b = ((const float4*)(src + lo))[1];
  u16x4 h0, h1;
  h0[0]=f2bf(a.x); h0[1]=f2bf(a.y); h0[2]=f2bf(a.z); h0[3]=f2bf(a.w);
  h1[0]=f2bf(b.x); h1[1]=f2bf(b.y); h1[2]=f2bf(b.z); h1[3]=f2bf(b.w);
  ((u16x4*)(dst + e0))[0] = h0;
  ((u16x4*)(dst + e0))[1] = h1;
}

// ---------------- router + x->bf16 convert fused ----------------
__global__ __launch_bounds__(64) void router_kernel(const float* __restrict__ x,
                                                    const float* __restrict__ Wr,
                                                    unsigned short* __restrict__ xb,
                                                    int* __restrict__ topk_e,
                                                    float* __restrict__ topk_w){
  const int t = blockIdx.x;
  const int lane = threadIdx.x;
  const float* xt = x + (size_t)t * D_HID;
  unsigned short* xbt = xb + (size_t)t * D_HID;
  float acc[E_NUM];
  #pragma unroll
  for (int e=0;e<E_NUM;e++) acc[e]=0.f;
  #pragma unroll
  for (int j=0;j<8;j++){
    const int d = j*256 + lane*4;
    const float4 v = *(const float4*)(xt + d);
    u16x4 h;
    h[0]=f2bf(v.x); h[1]=f2bf(v.y); h[2]=f2bf(v.z); h[3]=f2bf(v.w);
    *(u16x4*)(xbt + d) = h;
    #pragma unroll
    for (int e=0;e<E_NUM;e++){
      const float4 w = *(const float4*)(Wr + e*D_HID + d);
      acc[e] += v.x*w.x + v.y*w.y + v.z*w.z + v.w*w.w;
    }
  }
  #pragma unroll
  for (int e=0;e<E_NUM;e++){
    #pragma unroll
    for (int off=32; off>0; off>>=1) acc[e] += __shfl_xor(acc[e], off);
  }
  if (lane==0){
    float m = acc[0];
    #pragma unroll
    for (int e=1;e<E_NUM;e++) m = fmaxf(m, acc[e]);
    float p[E_NUM]; float s = 0.f;
    #pragma unroll
    for (int e=0;e<E_NUM;e++){ p[e] = expf(acc[e]-m); s += p[e]; }
    const float inv = 1.f/s;
    int i0=0; float b0=p[0];
    #pragma unroll
    for (int e=1;e<E_NUM;e++) if (p[e] > b0){ b0=p[e]; i0=e; }
    int i1=-1; float b1=-1.f;
    #pragma unroll
    for (int e=0;e<E_NUM;e++) if (e!=i0 && p[e] > b1){ b1=p[e]; i1=e; }
    topk_e[t*2+0]=i0; topk_e[t*2+1]=i1;
    topk_w[t*2+0]=b0*inv; topk_w[t*2+1]=b1*inv;
  }
}

// ---------------- deterministic expert-grouped list build + tile records ----------------
__global__ __launch_bounds__(1024) void build_lists_kernel(
    const int* __restrict__ topk_e, const float* __restrict__ topk_w,
    int* __restrict__ cnt, int* __restrict__ offs,
    int* __restrict__ assign_token, float* __restrict__ assign_w,
    int* __restrict__ token_slot,
    int* __restrict__ tile_rowbase, int* __restrict__ tile_e,
    int* __restrict__ tile_valid, int* __restrict__ n_rt)
{
  const int tid  = threadIdx.x;
  const int lane = tid & 63;
  const int wv   = tid >> 6;                 // 16 waves
  __shared__ int wsum[E_NUM][16];
  __shared__ int tot_s[E_NUM];
  __shared__ int offs_s[E_NUM];

  int   e_loc[4];
  float w_loc[4];
  #pragma unroll
  for (int j=0;j<4;j++){ e_loc[j]=topk_e[tid*4+j]; w_loc[j]=topk_w[tid*4+j]; }

  int c[E_NUM];
  #pragma unroll
  for (int e=0;e<E_NUM;e++){
    int s = 0;
    #pragma unroll
    for (int j=0;j<4;j++) s += (e_loc[j]==e) ? 1 : 0;
    c[e] = s;
  }
  int pre[E_NUM];
  #pragma unroll
  for (int e=0;e<E_NUM;e++){
    int v = c[e];
    #pragma unroll
    for (int off=1; off<64; off<<=1){
      int t = __shfl_up(v, off);
      if (lane >= off) v += t;
    }
    if (lane==63) wsum[e][wv] = v;
    pre[e] = v - c[e];
  }
  __syncthreads();
  if (tid < E_NUM){
    int s = 0;
    #pragma unroll
    for (int w=0; w<16; w++){ int t = wsum[tid][w]; wsum[tid][w] = s; s += t; }
    tot_s[tid] = s;
    cnt[tid]   = s;
  }
  __syncthreads();
  if (tid == 0){
    int s = 0;
    #pragma unroll
    for (int e=0;e<E_NUM;e++){ offs_s[e] = s; offs[e] = s; s += tot_s[e]; }
    int ntl = 0;
    for (int e=0;e<E_NUM;e++){
      for (int r=0; r<tot_s[e]; r+=256){
        tile_rowbase[ntl] = offs_s[e] + r;
        tile_e[ntl]       = e;
        int v = tot_s[e] - r; if (v > 256) v = 256;
        tile_valid[ntl]   = v;
        ntl++;
      }
    }
    n_rt[0] = ntl;
    for (int i=ntl;i<MAXT;i++){ tile_rowbase[i]=0; tile_e[i]=0; tile_valid[i]=0; }
  }
  __syncthreads();
  int local[E_NUM];
  #pragma unroll
  for (int e=0;e<E_NUM;e++) local[e]=0;
  #pragma unroll
  for (int j=0;j<4;j++){
    const int e = e_loc[j];
    int pos = 0;
    #pragma unroll
    for (int ee=0; ee<E_NUM; ee++)
      if (e == ee) pos = offs_s[ee] + wsum[ee][wv] + pre[ee] + local[ee];
    #pragma unroll
    for (int ee=0; ee<E_NUM; ee++) local[ee] += (e == ee) ? 1 : 0;
    const int entry = tid*4 + j;
    assign_token[pos] = entry >> 1;
    assign_w[pos]     = w_loc[j];
    token_slot[entry] = pos;
  }
}

// ================= fused gate+up GEMM, 2-phase dbuf + counted vmcnt (r5 schedule) =====
// 512 thr / 8 waves (4M x 2N), BM=256, BN=128, BK=64. LDS = 128 KB.
// Raw blocks [0,440): GEMM (XCD-swizzled). Raw blocks [440,504): down-weight converters
// that run concurrently with round-2 GEMM blocks (inter-block overlap).
__global__ __launch_bounds__(512,1) void gateup_fused(
    const unsigned short* __restrict__ xb,
    unsigned short* __restrict__ wb,
    const float* __restrict__ Wsd_f, const float* __restrict__ Wd_f,
    unsigned short* __restrict__ h_shared,
    unsigned short* __restrict__ h_routed,
    const int* __restrict__ tile_rowbase, const int* __restrict__ tile_e,
    const int* __restrict__ tile_valid, const int* __restrict__ n_rt,
    const int* __restrict__ assign_token)
{
  __shared__ __align__(16) char As[2][256*128];   // 64 KB
  __shared__ __align__(16) char Bg[2][128*128];   // 32 KB
  __shared__ __align__(16) char Bu[2][128*128];   // 32 KB

  const int tid  = threadIdx.x;
  const int braw = blockIdx.x;

  if (braw >= GU_GEMM){
    // -------- converter role: stream Wsd/Wd fp32 -> bf16 into wb --------
    const int cb = braw - GU_GEMM;                  // 0..63
    const long nchunk = (long)(W_TOT - O_WSD) / 8;  // 3,604,480
    for (long i = (long)cb*512 + tid; i < nchunk; i += (long)GU_CONV*512){
      const long e0 = (long)O_WSD + i * 8;
      const float* src; long lo;
      if (e0 < (long)O_WD){ src = Wsd_f; lo = e0 - O_WSD; } else { src = Wd_f; lo = e0 - O_WD; }
      const float4 va = ((const float4*)(src + lo))[0];
      const float4 vb = ((const float4*)(src + lo))[1];
      u16x4 h0, h1;
      h0[0]=f2bf(va.x); h0[1]=f2bf(va.y); h0[2]=f2bf(va.z); h0[3]=f2bf(va.w);
      h1[0]=f2bf(vb.x); h1[1]=f2bf(vb.y); h1[2]=f2bf(vb.z); h1[3]=f2bf(vb.w);
      ((u16x4*)(wb + e0))[0] = h0;
      ((u16x4*)(wb + e0))[1] = h1;
    }
    return;
  }

  // XCD-aware bijective swizzle within the GEMM role (440 = 8*55)
  const int b = (braw % 8) * (GU_GEMM/8) + braw / 8;

  const int lane = tid & 63;
  const int wave = tid >> 6;       // 0..7
  const int wr = wave >> 1;        // 0..3
  const int wc = wave & 1;         // 0..1

  int nt, rowbase, valid, gather;
  const unsigned short *wg_base, *wu_base;
  unsigned short* H; int N;
  if (b < GU_SH_BLK){
    nt = b >> 3; const int mtile = b & 7;       // 8 consecutive blocks share a weight panel
    rowbase = mtile*256; valid = 256; gather = 0;
    wg_base = wb + O_WSG + (size_t)(nt*128) * D_HID;
    wu_base = wb + O_WSU + (size_t)(nt*128) * D_HID;
    H = h_shared; N = FS_SH;
  } else {
    const int rb = b - GU_SH_BLK;
    const int tile = rb % MAXT;
    nt = rb / MAXT;                              // 0..10
    if (tile >= n_rt[0]) return;
    rowbase = tile_rowbase[tile];
    valid   = tile_valid[tile];
    const int e = tile_e[tile];
    gather = 1;
    wg_base = wb + O_WG + ((size_t)e*F_EXP + nt*128) * D_HID;
    wu_base = wb + O_WU + ((size_t)e*F_EXP + nt*128) * D_HID;
    H = h_routed; N = F_EXP;
  }

  f32x4 accg[4][4], accu[4][4];
  const f32x4 z = {0.f,0.f,0.f,0.f};
  #pragma unroll
  for (int m=0;m<4;m++)
    #pragma unroll
    for (int n=0;n<4;n++){ accg[m][n]=z; accu[m][n]=z; }

  const char* asrc[4];
  const int rowmax = rowbase + valid - 1;
  const int srccol = ((lane&7)<<4) ^ ((lane>>3)<<4);
  #pragma unroll
  for (int p=0;p<4;p++){
    const int row = wave*32 + p*8 + (lane>>3);
    int idx = rowbase + row;
    if (idx > rowmax) idx = rowmax;
    const size_t grow = gather ? (size_t)assign_token[idx] : (size_t)idx;
    asrc[p] = (const char*)(xb + grow * (size_t)D_HID) + srccol;
  }
  const int brow0 = wave*16 + (lane>>3);
  const char* gsrc = (const char*)(wg_base + (size_t)brow0 * D_HID) + srccol;
  const char* usrc = (const char*)(wu_base + (size_t)brow0 * D_HID) + srccol;
  const int pstrB = 8 * D_HID * 2;

  auto stage = [&](int bi, int kt){     // 8 loads per wave
    #pragma unroll
    for (int p=0;p<4;p++){
      __builtin_amdgcn_global_load_lds(
        (const AS1 void*)(asrc[p] + kt*128),
        (AS3 void*)(&As[bi][(wave*4 + p)*1024]), 16, 0, 0);
    }
    #pragma unroll
    for (int p=0;p<2;p++){
      __builtin_amdgcn_global_load_lds(
        (const AS1 void*)(gsrc + p*pstrB + kt*128),
        (AS3 void*)(&Bg[bi][(wave*2 + p)*1024]), 16, 0, 0);
      __builtin_amdgcn_global_load_lds(
        (const AS1 void*)(usrc + p*pstrB + kt*128),
        (AS3 void*)(&Bu[bi][(wave*2 + p)*1024]), 16, 0, 0);
    }
  };

  const int nK = D_HID / 64;   // 32
  stage(0, 0);                 // 8 loads in flight
  int cur = 0;
  for (int kt = 0; kt < nK; ++kt){
    if (kt + 1 < nK){
      stage(cur^1, kt+1);      // +8 loads: 16 outstanding
      asm volatile("s_waitcnt vmcnt(8)\n\ts_barrier" ::: "memory");
    } else {
      asm volatile("s_waitcnt vmcnt(0)\n\ts_barrier" ::: "memory");
    }
    #pragma unroll
    for (int kk=0;kk<2;kk++){
      const int kb = kk*64 + ((lane >> 4) << 4);
      bf16x8 a[4], bg[4], bu[4];
      #pragma unroll
      for (int m=0;m<4;m++){
        const int r = wr*64 + m*16 + (lane & 15);
        a[m] = *(const bf16x8*)(&As[cur][r*128 + (kb ^ ((r & 7) << 4))]);
      }
      #pragma unroll
      for (int n=0;n<4;n++){
        const int r = wc*64 + n*16 + (lane & 15);
        const int ofs = r*128 + (kb ^ ((r & 7) << 4));
        bg[n] = *(const bf16x8*)(&Bg[cur][ofs]);
        bu[n] = *(const bf16x8*)(&Bu[cur][ofs]);
      }
      #pragma unroll
      for (int m=0;m<4;m++)
        #pragma unroll
        for (int n=0;n<4;n++){
          accg[m][n] = __builtin_amdgcn_mfma_f32_16x16x32_bf16(a[m], bg[n], accg[m][n], 0,0,0);
          accu[m][n] = __builtin_amdgcn_mfma_f32_16x16x32_bf16(a[m], bu[n], accu[m][n], 0,0,0);
        }
    }
    asm volatile("s_barrier" ::: "memory");   // all waves done reading buf cur
    cur ^= 1;
  }

  const int colbase = nt*128 + wc*64;
  #pragma unroll
  for (int m=0;m<4;m++){
    #pragma unroll
    for (int r=0;r<4;r++){
      const int rr = wr*64 + m*16 + ((lane >> 4) << 2) + r;
      if (rr < valid){
        unsigned short* orow = H + (size_t)(rowbase + rr) * N;
        #pragma unroll
        for (int n=0;n<4;n++){
          const int col = colbase + n*16 + (lane & 15);
          const float g = accg[m][n][r];
          const float u = accu[m][n][r];
          const float h = (g / (1.f + __expf(-g))) * u;
          orow[col] = f2bf(h);
        }
      }
    }
  }
}

// ================= fused down GEMM, 2-phase dbuf + counted vmcnt (r5 schedule) =====
__global__ __launch_bounds__(512,1) void down_fused(
    const unsigned short* __restrict__ h_shared,
    const unsigned short* __restrict__ h_routed,
    const unsigned short* __restrict__ wb,
    float* __restrict__ out, float* __restrict__ y_routed,
    const int* __restrict__ tile_rowbase, const int* __restrict__ tile_e,
    const int* __restrict__ tile_valid, const int* __restrict__ n_rt,
    const float* __restrict__ assign_w)
{
  __shared__ __align__(16) char As[2][256*128];   // 64 KB
  __shared__ __align__(16) char Bs[2][128*128];   // 32 KB

  const int tid  = threadIdx.x;
  const int braw = blockIdx.x;
  const int b = (braw % 8) * (DN_GRID/8) + braw / 8;   // XCD swizzle (512 = 8*64)
  const int lane = tid & 63;
  const int wave = tid >> 6;
  const int wr = wave >> 1, wc = wave & 1;

  int nt, rowbase, valid, weighted, K;
  const unsigned short *A, *w_base;
  float* Out;
  if (b < DN_SH_BLK){
    nt = b >> 3; const int mtile = b & 7;
    rowbase = mtile*256; valid = 256; weighted = 0;
    A = h_shared; K = FS_SH;
    w_base = wb + O_WSD + (size_t)(nt*128) * FS_SH;
    Out = out;
  } else {
    const int rb = b - DN_SH_BLK;
    const int tile = rb % MAXT;
    nt = rb / MAXT;                              // 0..15
    if (tile >= n_rt[0]) return;
    rowbase = tile_rowbase[tile];
    valid   = tile_valid[tile];
    const int e = tile_e[tile];
    weighted = 1;
    A = h_routed; K = F_EXP;
    w_base = wb + O_WD + ((size_t)e*D_HID + nt*128) * F_EXP;
    Out = y_routed;
  }
  const size_t K2 = (size_t)K * 2;

  f32x4 acc[4][4];
  const f32x4 z = {0.f,0.f,0.f,0.f};
  #pragma unroll
  for (int m=0;m<4;m++)
    #pragma unroll
    for (int n=0;n<4;n++) acc[m][n]=z;

  const char* asrc[4];
  const int rowmax = rowbase + valid - 1;
  const int srccol = ((lane&7)<<4) ^ ((lane>>3)<<4);
  #pragma unroll
  for (int p=0;p<4;p++){
    const int row = wave*32 + p*8 + (lane>>3);
    int idx = rowbase + row;
    if (idx > rowmax) idx = rowmax;
    asrc[p] = (const char*)A + (size_t)idx * K2 + srccol;
  }
  const int brow0 = wave*16 + (lane>>3);
  const char* bsrc = (const char*)w_base + (size_t)brow0 * K2 + srccol;
  const size_t pstrB = 8 * K2;

  auto stage = [&](int bi, int kt){      // 6 loads per wave
    #pragma unroll
    for (int p=0;p<4;p++){
      __builtin_amdgcn_global_load_lds(
        (const AS1 void*)(asrc[p] + kt*128),
        (AS3 void*)(&As[bi][(wave*4 + p)*1024]), 16, 0, 0);
    }
    #pragma unroll
    for (int p=0;p<2;p++){
      __builtin_amdgcn_global_load_lds(
        (const AS1 void*)(bsrc + p*pstrB + kt*128),
        (AS3 void*)(&Bs[bi][(wave*2 + p)*1024]), 16, 0, 0);
    }
  };

  const int nK = K / 64;       // 44 or 22
  stage(0, 0);                 // 6 loads in flight
  int cur = 0;
  for (int kt = 0; kt < nK; ++kt){
    if (kt + 1 < nK){
      stage(cur^1, kt+1);      // +6: 12 outstanding
      asm volatile("s_waitcnt vmcnt(6)\n\ts_barrier" ::: "memory");
    } else {
      asm volatile("s_waitcnt vmcnt(0)\n\ts_barrier" ::: "memory");
    }
    #pragma unroll
    for (int kk=0;kk<2;kk++){
      const int kb = kk*64 + ((lane >> 4) << 4);
      bf16x8 a[4], bb[4];
      #pragma unroll
      for (int m=0;m<4;m++){
        const int r = wr*64 + m*16 + (lane & 15);
        a[m] = *(const bf16x8*)(&As[cur][r*128 + (kb ^ ((r & 7) << 4))]);
      }
      #pragma unroll
      for (int n=0;n<4;n++){
        const int r = wc*64 + n*16 + (lane & 15);
        bb[n] = *(const bf16x8*)(&Bs[cur][r*128 + (kb ^ ((r & 7) << 4))]);
      }
      #pragma unroll
      for (int m=0;m<4;m++)
        #pragma unroll
        for (int n=0;n<4;n++)
          acc[m][n] = __builtin_amdgcn_mfma_f32_16x16x32_bf16(a[m], bb[n], acc[m][n], 0,0,0);
    }
    asm volatile("s_barrier" ::: "memory");
    cur ^= 1;
  }

  const int colbase = nt*128 + wc*64;
  #pragma unroll
  for (int m=0;m<4;m++){
    #pragma unroll
    for (int r=0;r<4;r++){
      const int rr = wr*64 + m*16 + ((lane >> 4) << 2) + r;
      if (rr < valid){
        float w = 1.f;
        if (weighted) w = assign_w[rowbase + rr];
        float* orow = Out + (size_t)(rowbase + rr) * D_HID;
        #pragma unroll
        for (int n=0;n<4;n++){
          const int col = colbase + n*16 + (lane & 15);
          orow[col] = acc[m][n][r] * w;
        }
      }
    }
  }
}

// ---------------- combine: out += y[slot0] + y[slot1] ----------------
__global__ void combine_kernel(float* __restrict__ out, const float* __restrict__ y,
                               const int* __restrict__ token_slot){
  const int i  = blockIdx.x * blockDim.x + threadIdx.x;
  const int t  = i >> 9;
  const int r4 = i & 511;
  const int s0 = token_slot[t*2+0];
  const int s1 = token_slot[t*2+1];
  const float4 a = ((const float4*)(y + (size_t)s0 * D_HID))[r4];
  const float4 b = ((const float4*)(y + (size_t)s1 * D_HID))[r4];
  float4 o = ((float4*)out)[i];
  o.x += a.x + b.x; o.y += a.y + b.y; o.z += a.z + b.z; o.w += a.w + b.w;
  ((float4*)out)[i] = o;
}

extern "C" void kernel_launch(void* const* d_in, const int* in_sizes, int n_in,
                              void* d_out, int out_size, void* d_ws, size_t ws_size,
                              hipStream_t stream){
  const float* x   = (const float*)d_in[0];
  const float* Wr  = (const float*)d_in[1];
  const float* Wg  = (const float*)d_in[2];
  const float* Wu  = (const float*)d_in[3];
  const float* Wd  = (const float*)d_in[4];
  const float* Wsg = (const float*)d_in[5];
  const float* Wsu = (const float*)d_in[6];
  const float* Wsd = (const float*)d_in[7];
  float* out = (float*)d_out;
  (void)in_sizes; (void)n_in; (void)out_size; (void)ws_size;

  char* ws = (char*)d_ws;
  size_t off = 0;
  auto alloc = [&](size_t bytes)->char*{
    char* p = ws + off; off += (bytes + 255) & ~(size_t)255; return p;
  };

  unsigned short* wb       = (unsigned short*)alloc((size_t)W_TOT * 2);
  unsigned short* xb       = (unsigned short*)alloc((size_t)T_TOK * D_HID * 2);
  unsigned short* h_shared = (unsigned short*)alloc((size_t)T_TOK * FS_SH * 2);
  unsigned short* h_routed = (unsigned short*)alloc((size_t)T_TOK * 2 * F_EXP * 2);
  float*          y_routed = (float*)alloc((size_t)T_TOK * 2 * D_HID * 4);
  int*   topk_e       = (int*)alloc(T_TOK*2*sizeof(int));
  float* topk_w       = (float*)alloc(T_TOK*2*sizeof(float));
  int*   cnt          = (int*)alloc(E_NUM*sizeof(int));
  int*   offs         = (int*)alloc(E_NUM*sizeof(int));
  int*   assign_token = (int*)alloc(T_TOK*2*sizeof(int));
  float* assign_w     = (float*)alloc(T_TOK*2*sizeof(float));
  int*   token_slot   = (int*)alloc(T_TOK*2*sizeof(int));
  int*   tile_rowbase = (int*)alloc(MAXT*sizeof(int));
  int*   tile_e       = (int*)alloc(MAXT*sizeof(int));
  int*   tile_valid   = (int*)alloc(MAXT*sizeof(int));
  int*   n_rt         = (int*)alloc(sizeof(int));

  router_kernel<<<T_TOK, 64, 0, stream>>>(x, Wr, xb, topk_e, topk_w);
  build_lists_kernel<<<1, 1024, 0, stream>>>(topk_e, topk_w, cnt, offs,
      assign_token, assign_w, token_slot, tile_rowbase, tile_e, tile_valid, n_rt);
  // convert only gate/up region; gateup_fused's trailing converter blocks do the down region
  convert_w_kernel<<<O_WSD/8/256, 256, 0, stream>>>(Wsg, Wsu, Wg, Wu, wb);

  gateup_fused<<<GU_GEMM + GU_CONV, 512, 0, stream>>>(
      xb, wb, Wsd, Wd, h_shared, h_routed, tile_rowbase, tile_e, tile_valid, n_rt, assign_token);
  down_fused<<<DN_GRID, 512, 0, stream>>>(
      h_shared, h_routed, wb, out, y_routed, tile_rowbase, tile_e, tile_valid, n_rt, assign_w);

  combine_kernel<<<(T_TOK*D_HID/4)/256, 256, 0, stream>>>(out, y_routed, token_slot);
}